// Round 12
// baseline (238.948 us; speedup 1.0000x reference)
//
#include <hip/hip_runtime.h>

#define N_NODES 100000
#define N_EDGES 3200000
#define CH 256

#define GRID_QK 1563     // 64 nodes/block
#define GRID_POOL 512
#define YCOPY 16

// segmented-sum geometry: 8 node-ranges x 32 edge-slices, XCD-cohort swizzled.
// hits/entry = (EPSL/NR)/RANGE = 1.0 (vs 0.5 at NR4/SL64): slab+fold traffic
// halves to 12.8+12.8 MB at identical grid (256 = 1 block/CU) and occupancy.
#define NR 8
#define RANGE 12500      // nodes per range; LDS acc = 50 KB static
#define SL 32            // edge slices
#define EPSL 100000      // edges per slice = N_EDGES / SL (exact)
#define QEPS 25000       // EPSL/4 int4 loads per slice
#define GP 391           // ceil(N_NODES/256) fold blocks -> ptot entries

// ---- ws layout (float offsets) ----
#define OFF_TOTAL 0
#define OFF_PTOT  16       // 512 (only GP used)
#define OFF_YU16  528      // 4096
#define OFF_Q     4624     // 100000
#define OFF_K     104624   // 100000
#define OFF_AWU   204624   // 100000
#define OFF_PART  304624   // NR*SL*RANGE = 3,200,000 floats (12.8 MB)
// end = 3,504,624 floats ~= 14 MiB

// q[n]=x[n,:].Wq+bq, k[n]=x[n,:].Wk+bk. 16-lane dot groups, 4 shuffle levels.
__global__ __launch_bounds__(256) void k_qk(const float* __restrict__ x,
                                            const float* __restrict__ Wq,
                                            const float* __restrict__ bq,
                                            const float* __restrict__ Wk,
                                            const float* __restrict__ bk,
                                            float* __restrict__ q,
                                            float* __restrict__ k,
                                            float* __restrict__ yu16) {
    int t = threadIdx.x;
    if (blockIdx.x < 16) yu16[blockIdx.x * 256 + t] = 0.0f;  // zero for k_pool atomics
    int w = t >> 6, lane = t & 63;
    int g = lane >> 4, seg = lane & 15;
    float4 wq4[4], wk4[4];
    #pragma unroll
    for (int j = 0; j < 4; ++j) {
        wq4[j] = ((const float4*)Wq)[seg + 16 * j];
        wk4[j] = ((const float4*)Wk)[seg + 16 * j];
    }
    float bqs = bq[0], bks = bk[0];
    int base = blockIdx.x * 64 + w * 16 + g;
    #pragma unroll
    for (int i = 0; i < 4; ++i) {
        int n = base + i * 4;
        if (n < N_NODES) {
            const float4* xr = (const float4*)(x + (size_t)n * CH);
            float dq = 0.0f, dk = 0.0f;
            #pragma unroll
            for (int j = 0; j < 4; ++j) {
                float4 xv = xr[seg + 16 * j];
                dq = fmaf(xv.x, wq4[j].x, fmaf(xv.y, wq4[j].y,
                     fmaf(xv.z, wq4[j].z, fmaf(xv.w, wq4[j].w, dq))));
                dk = fmaf(xv.x, wk4[j].x, fmaf(xv.y, wk4[j].y,
                     fmaf(xv.z, wk4[j].z, fmaf(xv.w, wk4[j].w, dk))));
            }
            dq += __shfl_down(dq, 8); dq += __shfl_down(dq, 4);
            dq += __shfl_down(dq, 2); dq += __shfl_down(dq, 1);
            dk += __shfl_down(dk, 8); dk += __shfl_down(dk, 4);
            dk += __shfl_down(dk, 2); dk += __shfl_down(dk, 1);
            if (seg == 0) { q[n] = dq + bqs; k[n] = dk + bks; }
        }
    }
}

// Segmented sum, stage 1. NR=8 x SL=32: block (slice s, range r) scans 100K
// edges 4-wide (8x16B index loads in flight per latency step), keeps the 1/8
// in-range, gathers q/k (L2-resident), leaky+exp, ds_add into 50KB LDS, writes
// one dense 50KB slab (hits/entry = 1.0 -> slab total 12.8 MB, half of R11).
// XCD-cohort swizzle keeps a slice's 8 range-blocks on one XCD L2 (perf-only).
__global__ __launch_bounds__(1024) void k_acc(const int* __restrict__ ei,
                                              const float* __restrict__ q,
                                              const float* __restrict__ k,
                                              float* __restrict__ partial) {
    __shared__ float acc[RANGE];   // 50,000 B static LDS
    int t = threadIdx.x;
    int xcd = blockIdx.x & 7;
    int inner = blockIdx.x >> 3;        // 0..31
    int r = inner & 7;                  // range 0..7
    int s = (inner >> 3) * 8 + xcd;     // slice 0..31; s%8 == xcd
    for (int i = t; i < RANGE; i += 1024) acc[i] = 0.0f;
    __syncthreads();
    int r0 = r * RANGE;
    const int4* r4p = (const int4*)ei + (size_t)s * QEPS;
    const int4* c4p = (const int4*)(ei + N_EDGES) + (size_t)s * QEPS;
    for (int base = t; base < QEPS; base += 4096) {
        int4 rv0, rv1, rv2, rv3, cv0, cv1, cv2, cv3;
        int i1 = base + 1024, i2 = base + 2048, i3 = base + 3072;
        bool h1 = i1 < QEPS, h2 = i2 < QEPS, h3 = i3 < QEPS;
        // issue all index loads first: up to 8x16B in flight per thread
        rv0 = r4p[base];            cv0 = c4p[base];
        if (h1) { rv1 = r4p[i1];    cv1 = c4p[i1]; }
        if (h2) { rv2 = r4p[i2];    cv2 = c4p[i2]; }
        if (h3) { rv3 = r4p[i3];    cv3 = c4p[i3]; }
        #define DO4(rv, cv)                                                   \
        {                                                                     \
            unsigned o0 = (unsigned)(rv.x - r0);                              \
            unsigned o1 = (unsigned)(rv.y - r0);                              \
            unsigned o2 = (unsigned)(rv.z - r0);                              \
            unsigned o3 = (unsigned)(rv.w - r0);                              \
            if (o0 < RANGE) {                                                 \
                float v = q[rv.x] * k[cv.x];                                  \
                atomicAdd(&acc[o0], __expf(fmaxf(v, 0.2f * v)));              \
            }                                                                 \
            if (o1 < RANGE) {                                                 \
                float v = q[rv.y] * k[cv.y];                                  \
                atomicAdd(&acc[o1], __expf(fmaxf(v, 0.2f * v)));              \
            }                                                                 \
            if (o2 < RANGE) {                                                 \
                float v = q[rv.z] * k[cv.z];                                  \
                atomicAdd(&acc[o2], __expf(fmaxf(v, 0.2f * v)));              \
            }                                                                 \
            if (o3 < RANGE) {                                                 \
                float v = q[rv.w] * k[cv.w];                                  \
                atomicAdd(&acc[o3], __expf(fmaxf(v, 0.2f * v)));              \
            }                                                                 \
        }
        DO4(rv0, cv0);
        if (h1) DO4(rv1, cv1);
        if (h2) DO4(rv2, cv2);
        if (h3) DO4(rv3, cv3);
        #undef DO4
    }
    __syncthreads();
    float* dst = partial + ((size_t)r * SL + s) * RANGE;
    for (int i = t; i < RANGE; i += 1024) dst[i] = acc[i];
}

// Stage 2: awu[n] = sum_s partial[range(n)][s][n%RANGE]; ptot[blk] = block total partial
__global__ __launch_bounds__(256) void k_fold(const float* __restrict__ partial,
                                              float* __restrict__ awu,
                                              float* __restrict__ ptot) {
    int t = threadIdx.x;
    int n = blockIdx.x * 256 + t;
    float s = 0.0f;
    if (n < N_NODES) {
        int r = n / RANGE, off = n % RANGE;   // magic-mul div
        const float* p = partial + (size_t)r * SL * RANGE + off;
        #pragma unroll 8
        for (int g = 0; g < SL; ++g) s += p[(size_t)g * RANGE];
        awu[n] = s;
    }
    float rsum = s;
    #pragma unroll
    for (int off = 32; off; off >>= 1) rsum += __shfl_down(rsum, off);
    __shared__ float sm[4];
    if ((t & 63) == 0) sm[t >> 6] = rsum;
    __syncthreads();
    if (t == 0) ptot[blockIdx.x] = sm[0] + sm[1] + sm[2] + sm[3];
}

// total inline from ptot; yu16 atomic partials; aw_out = awu/total
__global__ __launch_bounds__(256) void k_pool(const float* __restrict__ x,
                                              const float* __restrict__ awu,
                                              const float* __restrict__ ptot,
                                              float* __restrict__ totalp,
                                              float* __restrict__ yu16,
                                              float* __restrict__ aw_out) {
    int t = threadIdx.x, s = t >> 6, g = t & 63;
    // reduce ptot[0..GP) -> total (every block, cheap)
    float ts = ptot[t] + ((t + 256 < GP) ? ptot[t + 256] : 0.0f);
    #pragma unroll
    for (int off = 32; off; off >>= 1) ts += __shfl_down(ts, off);
    __shared__ float sm[4];
    __shared__ float tot;
    if (g == 0) sm[s] = ts;
    __syncthreads();
    if (t == 0) {
        tot = sm[0] + sm[1] + sm[2] + sm[3];
        if (blockIdx.x == 0) totalp[0] = tot;
    }
    __syncthreads();
    float inv = 1.0f / tot;

    const float4* X4 = (const float4*)x;
    float4 acc = make_float4(0.f, 0.f, 0.f, 0.f);
    for (int base = blockIdx.x * 8; base < N_NODES; base += GRID_POOL * 8) {
        float a0 = awu[base + s];
        float a1 = awu[base + 4 + s];
        float4 x0 = X4[(size_t)(base + s) * 64 + g];
        float4 x1 = X4[(size_t)(base + 4 + s) * 64 + g];
        acc.x = fmaf(a0, x0.x, acc.x); acc.y = fmaf(a0, x0.y, acc.y);
        acc.z = fmaf(a0, x0.z, acc.z); acc.w = fmaf(a0, x0.w, acc.w);
        acc.x = fmaf(a1, x1.x, acc.x); acc.y = fmaf(a1, x1.y, acc.y);
        acc.z = fmaf(a1, x1.z, acc.z); acc.w = fmaf(a1, x1.w, acc.w);
    }
    __shared__ float4 tmp4[4][64];
    tmp4[s][g] = acc;
    __syncthreads();
    const float* tmp = (const float*)tmp4;
    float sum = tmp[0 * 256 + t] + tmp[1 * 256 + t] + tmp[2 * 256 + t] + tmp[3 * 256 + t];
    atomicAdd(&yu16[(blockIdx.x & (YCOPY - 1)) * 256 + t], sum);
    for (int i = blockIdx.x * 256 + t; i < N_NODES; i += GRID_POOL * 256)
        aw_out[i] = awu[i] * inv;
}

// grid 8: block j -> out[j*32 .. j*32+32)
__global__ __launch_bounds__(256) void k_final(const float* __restrict__ yu16,
                                               const float* __restrict__ totalp,
                                               const float* __restrict__ Wv,
                                               const float* __restrict__ bv,
                                               float* __restrict__ out) {
    __shared__ float ysh[256];
    __shared__ float red[256];
    int t = threadIdx.x;
    float inv = 1.0f / totalp[0];
    float yv = 0.0f;
    #pragma unroll
    for (int j = 0; j < YCOPY; ++j) yv += yu16[j * 256 + t];
    ysh[t] = yv * inv;
    __syncthreads();
    int c = blockIdx.x * 32 + (t & 31), rg = t >> 5;
    float acc = 0.0f;
    #pragma unroll
    for (int j = 0; j < 32; ++j) {
        int kk = rg * 32 + j;
        acc = fmaf(ysh[kk], Wv[(size_t)kk * CH + c], acc);
    }
    red[t] = acc;
    __syncthreads();
    if (t < 32) {
        float sv = 0.0f;
        #pragma unroll
        for (int j = 0; j < 8; ++j) sv += red[j * 32 + t];
        out[blockIdx.x * 32 + t] = sv + bv[blockIdx.x * 32 + t];
    }
}

extern "C" void kernel_launch(void* const* d_in, const int* in_sizes, int n_in,
                              void* d_out, int out_size, void* d_ws, size_t ws_size,
                              hipStream_t stream) {
    const float* x  = (const float*)d_in[0];
    const int*   ei = (const int*)d_in[1];
    const float* Wq = (const float*)d_in[2];
    const float* bq = (const float*)d_in[3];
    const float* Wk = (const float*)d_in[4];
    const float* bk = (const float*)d_in[5];
    const float* Wv = (const float*)d_in[6];
    const float* bv = (const float*)d_in[7];
    float* out = (float*)d_out;
    float* ws  = (float*)d_ws;

    float* totalp  = ws + OFF_TOTAL;
    float* ptot    = ws + OFF_PTOT;
    float* yu16    = ws + OFF_YU16;
    float* q       = ws + OFF_Q;
    float* k       = ws + OFF_K;
    float* awu     = ws + OFF_AWU;
    float* partial = ws + OFF_PART;

    hipLaunchKernelGGL(k_qk, dim3(GRID_QK), dim3(256), 0, stream,
                       x, Wq, bq, Wk, bk, q, k, yu16);
    hipLaunchKernelGGL(k_acc, dim3(NR * SL), dim3(1024), 0, stream,
                       ei, q, k, partial);
    hipLaunchKernelGGL(k_fold, dim3(GP), dim3(256), 0, stream,
                       partial, awu, ptot);
    hipLaunchKernelGGL(k_pool, dim3(GRID_POOL), dim3(256), 0, stream,
                       x, awu, ptot, totalp, yu16, out + CH);
    hipLaunchKernelGGL(k_final, dim3(8), dim3(256), 0, stream,
                       yu16, totalp, Wv, bv, out);
}